// Round 3
// baseline (18474.400 us; speedup 1.0000x reference)
//
#include <hip/hip_runtime.h>
#include <math.h>

#define D       256
#define NROWS   32768      // 8 * 4096
#define CODES   8192
#define QOFF    8388608    // index output offset (floats) in d_out

// ---------------- coarse kernel config ----------------
#define BM      128
#define BN      128
#define NSPL    4
#define SPLC    (CODES / NSPL)    // 2048
#define NCHUNK  (SPLC / BN)       // 16
#define PRESCAN 2

// rigorous collect margin: 2*(2u+u^2)*||x||*||e||max + slack, u=2^-8 (bf16 rn)
#define MARG_COEF 0.034f
#define MARG_ABS  0.10f

// ---------------- ws layout (bytes) ----------------
#define OFF_AH    0ull               // 32768*256*2      = 16777216
#define OFF_X2    16777216ull        // 32768*4
#define OFF_NX    16908288ull        // 32768*4
#define OFF_E2    17039360ull        // 8192*4
#define OFF_RM    17072128ull        // 32768*4 (unsigned float-bits)
#define OFF_PK    17203200ull        // 32768*8
#define OFF_MISC  17465344ull        // [0]=cnt, [1]=cnt2, [2]=neMaxBits
#define OFF_L2    17465600ull        // 1048576*4
#define OFF_CAND  21659904ull        // uint2 entries, runtime cap
#define CAP2      1048576u
#define WS_NEED2  (OFF_CAND + 16777216ull)   // >= 2M candidate entries

typedef __attribute__((ext_vector_type(8))) short bf16x8;
typedef __attribute__((ext_vector_type(4))) float f32x4;

// Involutive LDS swizzle (verified 0-conflict in round 2): byte bits 8:7 -> 5:4
__device__ __forceinline__ int SW(int b) { return b ^ (((b >> 7) & 3) << 4); }

__device__ __forceinline__ void gload16(const void* g, void* l) {
  __builtin_amdgcn_global_load_lds(
      (const __attribute__((address_space(1))) unsigned int*)g,
      (__attribute__((address_space(3))) unsigned int*)l, 16, 0, 0);
}

__device__ __forceinline__ unsigned short bf16rn(float x) {
  unsigned u = __float_as_uint(x);
  return (unsigned short)((u + 0x7fffu + ((u >> 16) & 1u)) >> 16);
}

// ---------------------------------------------------------------------------
// init: zero counters, rowMin=+inf, pKey=~0
// ---------------------------------------------------------------------------
__global__ __launch_bounds__(256) void init_kernel(unsigned* __restrict__ misc,
                                                   unsigned* __restrict__ rowMinU,
                                                   unsigned long long* __restrict__ pKey) {
  int i = blockIdx.x * 256 + threadIdx.x;   // grid 128*256 = 32768
  if (i == 0) { misc[0] = 0u; misc[1] = 0u; misc[2] = 0u; }
  rowMinU[i] = 0x7F800000u;
  pKey[i] = ~0ull;
}

// ---------------------------------------------------------------------------
// prep: bf16 h-planes of x and embed + squared norms + neMax.
// Reduction tree identical to rounds 1-2 (proven to match ref).
// ---------------------------------------------------------------------------
__global__ __launch_bounds__(256) void prep_kernel(const float* __restrict__ x,
                                                   const float* __restrict__ embed,
                                                   unsigned short* __restrict__ A_h,
                                                   unsigned short* __restrict__ E_h,
                                                   float* __restrict__ x2,
                                                   float* __restrict__ nx,
                                                   float* __restrict__ e2,
                                                   unsigned* __restrict__ misc) {
  int wid  = threadIdx.x >> 6;
  int lane = threadIdx.x & 63;
  int rid  = blockIdx.x * 4 + wid;   // 0..40959
  const float* src;
  unsigned short* dst;
  if (rid < NROWS) { src = x + (size_t)rid * D;               dst = A_h + (size_t)rid * D; }
  else             { src = embed + (size_t)(rid - NROWS) * D; dst = E_h + (size_t)(rid - NROWS) * D; }
  float4 v = *(const float4*)(src + lane * 4);
  ushort4 hv = make_ushort4(bf16rn(v.x), bf16rn(v.y), bf16rn(v.z), bf16rn(v.w));
  *(ushort4*)(dst + lane * 4) = hv;
  float p = v.x * v.x + v.y * v.y + v.z * v.z + v.w * v.w;
  #pragma unroll
  for (int off = 32; off > 0; off >>= 1) p += __shfl_down(p, off);
  if (lane == 0) {
    float n = sqrtf(p);
    if (rid < NROWS) { x2[rid] = p; nx[rid] = n; }
    else { e2[rid - NROWS] = p; atomicMax(&misc[2], __float_as_uint(n)); }
  }
}

// ---------------------------------------------------------------------------
// coarse: 1-plane bf16 MFMA GEMM, running per-row min of coarse d2, and
// collection of candidates within a rigorous margin of the running min.
// Tile 128x128, 4 waves (2x2), 4x4 frags of 16x16x32. Grid (256, NSPL).
// ---------------------------------------------------------------------------
__global__ __launch_bounds__(256) void coarse_kernel(
    const unsigned short* __restrict__ A_h,
    const unsigned short* __restrict__ E_h,
    const float* __restrict__ x2g, const float* __restrict__ e2g,
    const float* __restrict__ nxg, const unsigned* __restrict__ miscR,
    unsigned* __restrict__ rowMinU,
    uint2* __restrict__ cand, unsigned* __restrict__ cnt, unsigned capN) {
  __shared__ __align__(16) char As[8192];
  __shared__ __align__(16) char Bs[8192];
  __shared__ float seedBuf[2][128];

  const int tid  = threadIdx.x;
  const int lane = tid & 63;
  const int wave = tid >> 6;
  const int wm = wave >> 1, wn = wave & 1;
  const int l15 = lane & 15, lh = lane >> 4;
  const int rowBase = blockIdx.x * BM;
  const int split   = blockIdx.y;

  int swA[4], swB[4];
  #pragma unroll
  for (int f = 0; f < 4; f++) {
    swA[f] = SW((((wm * 64 + f * 16 + l15)) << 6) | (lh << 4));
    swB[f] = SW((((wn * 64 + f * 16 + l15)) << 6) | (lh << 4));
  }

  int stRow[2], stOff[2], stDst[2];
  #pragma unroll
  for (int i = 0; i < 2; i++) {
    int q = i * 256 + tid;           // 0..511 (16B slots of the 8KB tile)
    int u = SW(q << 4);
    stRow[i] = u >> 6;
    stOff[i] = u & 63;
    stDst[i] = (q & ~63) * 16;
  }

  const float neMaxF = __uint_as_float(miscR[2]);

  float x2r[16], rowC[16];
  int rowIdx[16];
  #pragma unroll
  for (int fm = 0; fm < 4; fm++)
    #pragma unroll
    for (int r = 0; r < 4; r++) {
      int s = fm * 4 + r;
      int row = rowBase + wm * 64 + fm * 16 + lh * 4 + r;
      rowIdx[s] = row;
      x2r[s] = x2g[row];
      rowC[s] = fmaf(MARG_COEF * nxg[row], neMaxF, MARG_ABS);
    }

  float runm[16];
  #pragma unroll
  for (int s = 0; s < 16; s++) runm[s] = INFINITY;

  // ---------------- prescan (seed the running min) ----------------
  for (int cc = 0; cc < PRESCAN; ++cc) {
    const int cBase = split * SPLC + cc * BN;
    f32x4 acc[4][4];
    #pragma unroll
    for (int i = 0; i < 4; i++)
      #pragma unroll
      for (int j = 0; j < 4; j++) acc[i][j] = (f32x4)(0.0f);
    for (int kb = 0; kb < 8; ++kb) {
      __syncthreads();
      #pragma unroll
      for (int i = 0; i < 2; i++) {
        gload16((const char*)A_h + (size_t)(rowBase + stRow[i]) * 512 + kb * 64 + stOff[i], As + stDst[i]);
        gload16((const char*)E_h + (size_t)(cBase   + stRow[i]) * 512 + kb * 64 + stOff[i], Bs + stDst[i]);
      }
      __syncthreads();
      bf16x8 af[4], bf[4];
      #pragma unroll
      for (int f = 0; f < 4; f++) { af[f] = *(const bf16x8*)(As + swA[f]); bf[f] = *(const bf16x8*)(Bs + swB[f]); }
      #pragma unroll
      for (int fm = 0; fm < 4; fm++)
        #pragma unroll
        for (int fn = 0; fn < 4; fn++)
          acc[fm][fn] = __builtin_amdgcn_mfma_f32_16x16x32_bf16(af[fm], bf[fn], acc[fm][fn], 0, 0, 0);
    }
    #pragma unroll
    for (int fn = 0; fn < 4; fn++) {
      float e2c = e2g[cBase + wn * 64 + fn * 16 + l15];
      #pragma unroll
      for (int fm = 0; fm < 4; fm++)
        #pragma unroll
        for (int r = 0; r < 4; r++) {
          int s = fm * 4 + r;
          float d2 = fmaf(acc[fm][fn][r], -2.0f, x2r[s] + e2c);
          runm[s] = fminf(runm[s], d2);
        }
    }
  }
  // reduce seed across l15 lanes and the two wn waves
  #pragma unroll
  for (int s = 0; s < 16; s++)
    #pragma unroll
    for (int off = 1; off < 16; off <<= 1)
      runm[s] = fminf(runm[s], __shfl_xor(runm[s], off));
  __syncthreads();
  if (l15 == 0) {
    #pragma unroll
    for (int s = 0; s < 16; s++) seedBuf[wn][rowIdx[s] - rowBase] = runm[s];
  }
  __syncthreads();
  float thr[16];
  #pragma unroll
  for (int s = 0; s < 16; s++) {
    int rl = rowIdx[s] - rowBase;
    runm[s] = fminf(seedBuf[0][rl], seedBuf[1][rl]);
    thr[s]  = runm[s] + rowC[s];
  }

  // ---------------- main scan with collection ----------------
  for (int cc = 0; cc < NCHUNK; ++cc) {
    const int cBase = split * SPLC + cc * BN;
    f32x4 acc[4][4];
    #pragma unroll
    for (int i = 0; i < 4; i++)
      #pragma unroll
      for (int j = 0; j < 4; j++) acc[i][j] = (f32x4)(0.0f);
    for (int kb = 0; kb < 8; ++kb) {
      __syncthreads();
      #pragma unroll
      for (int i = 0; i < 2; i++) {
        gload16((const char*)A_h + (size_t)(rowBase + stRow[i]) * 512 + kb * 64 + stOff[i], As + stDst[i]);
        gload16((const char*)E_h + (size_t)(cBase   + stRow[i]) * 512 + kb * 64 + stOff[i], Bs + stDst[i]);
      }
      __syncthreads();
      bf16x8 af[4], bf[4];
      #pragma unroll
      for (int f = 0; f < 4; f++) { af[f] = *(const bf16x8*)(As + swA[f]); bf[f] = *(const bf16x8*)(Bs + swB[f]); }
      #pragma unroll
      for (int fm = 0; fm < 4; fm++)
        #pragma unroll
        for (int fn = 0; fn < 4; fn++)
          acc[fm][fn] = __builtin_amdgcn_mfma_f32_16x16x32_bf16(af[fm], bf[fn], acc[fm][fn], 0, 0, 0);
    }
    #pragma unroll
    for (int fn = 0; fn < 4; fn++) {
      int col = cBase + wn * 64 + fn * 16 + l15;
      float e2c = e2g[col];
      #pragma unroll
      for (int fm = 0; fm < 4; fm++)
        #pragma unroll
        for (int r = 0; r < 4; r++) {
          int s = fm * 4 + r;
          float d2 = fmaf(acc[fm][fn][r], -2.0f, x2r[s] + e2c);
          if (d2 <= thr[s]) {
            unsigned pos = atomicAdd(cnt, 1u);
            if (pos < capN)
              cand[pos] = make_uint2((unsigned)((rowIdx[s] << 13) | col), __float_as_uint(d2));
          }
          runm[s] = fminf(runm[s], d2);
        }
    }
    #pragma unroll
    for (int s = 0; s < 16; s++) thr[s] = runm[s] + rowC[s];
  }

  // ---------------- final per-row coarse min ----------------
  #pragma unroll
  for (int s = 0; s < 16; s++)
    #pragma unroll
    for (int off = 1; off < 16; off <<= 1)
      runm[s] = fminf(runm[s], __shfl_xor(runm[s], off));
  if (l15 == 0) {
    #pragma unroll
    for (int s = 0; s < 16; s++)
      atomicMin(&rowMinU[rowIdx[s]], __float_as_uint(fmaxf(runm[s], 0.0f)));
  }
}

// ---------------------------------------------------------------------------
// filter: re-test candidates against the FINAL rowMin, compact survivors.
// ---------------------------------------------------------------------------
__global__ __launch_bounds__(256) void filter_kernel(const uint2* __restrict__ cand,
                                                     unsigned* __restrict__ misc,
                                                     const unsigned* __restrict__ rowMinU,
                                                     const float* __restrict__ nxg,
                                                     unsigned* __restrict__ list2,
                                                     unsigned capN) {
  unsigned total = misc[0]; if (total > capN) total = capN;
  float neMaxF = __uint_as_float(misc[2]);
  unsigned stride = gridDim.x * 256;
  for (unsigned i = blockIdx.x * 256 + threadIdx.x; i < total; i += stride) {
    uint2 en = cand[i];
    unsigned row = en.x >> 13;
    float d2c = __uint_as_float(en.y);
    float rm  = __uint_as_float(rowMinU[row]);
    float rc  = fmaf(MARG_COEF * nxg[row], neMaxF, MARG_ABS);
    if (d2c <= rm + rc) {
      unsigned p = atomicAdd(&misc[1], 1u);
      if (p < CAP2) list2[p] = en.x;
    }
  }
}

// ---------------------------------------------------------------------------
// refine: wave-per-survivor fp64 dot, exact ref combine, u64 atomicMin key.
// ---------------------------------------------------------------------------
__global__ __launch_bounds__(256) void refine_kernel(const float* __restrict__ x,
                                                     const float* __restrict__ embed,
                                                     const float* __restrict__ x2g,
                                                     const float* __restrict__ e2g,
                                                     const unsigned* __restrict__ misc,
                                                     const unsigned* __restrict__ list2,
                                                     unsigned long long* __restrict__ pKey) {
  unsigned total = misc[1]; if (total > CAP2) total = CAP2;
  int lane = threadIdx.x & 63;
  unsigned wv = (blockIdx.x * 256 + threadIdx.x) >> 6;
  unsigned nw = (gridDim.x * 256) >> 6;
  for (unsigned i = wv; i < total; i += nw) {
    unsigned pk = list2[i];
    int row = (int)(pk >> 13), col = (int)(pk & 8191u);
    float4 xv = *(const float4*)&x[(size_t)row * D + lane * 4];
    float4 ev = *(const float4*)&embed[(size_t)col * D + lane * 4];
    double s = (double)xv.x * (double)ev.x;
    s = fma((double)xv.y, (double)ev.y, s);
    s = fma((double)xv.z, (double)ev.z, s);
    s = fma((double)xv.w, (double)ev.w, s);
    #pragma unroll
    for (int off = 32; off > 0; off >>= 1) s += __shfl_down(s, off);
    if (lane == 0) {
      float xef = (float)s;
      float ss  = __fadd_rn(x2g[row], e2g[col]);
      float d2  = __fsub_rn(ss, __fmul_rn(2.0f, xef));
      d2 = fmaxf(d2, 0.0f);
      float sq = sqrtf(d2);
      unsigned long long key =
          ((unsigned long long)__float_as_uint(sq) << 32) | (unsigned)col;
      atomicMin(pKey + row, key);
    }
  }
}

// ---------------------------------------------------------------------------
// finalize: gather codes + write index as float.
// ---------------------------------------------------------------------------
__global__ __launch_bounds__(256) void final_kernel(const float* __restrict__ embed,
                                                    const unsigned long long* __restrict__ pKey,
                                                    float* __restrict__ outQ,
                                                    float* __restrict__ indF) {
  int wid  = threadIdx.x >> 6;
  int lane = threadIdx.x & 63;
  int row  = blockIdx.x * 4 + wid;
  unsigned long long k = pKey[row];
  int idx = (int)(k & 8191ull);
  float4 v = *(const float4*)&embed[(size_t)idx * D + lane * 4];
  *(float4*)&outQ[(size_t)row * D + lane * 4] = v;
  if (lane == 0) indF[row] = (float)idx;
}

// ===========================================================================
// Fallback fp32 path (round-1, proven) — used if ws_size < WS_NEED2.
// ===========================================================================
#define BM_F 128
#define BN_F 128
#define BK_F 32
#define NSPLIT_F 4
#define SPLIT_CF (CODES / NSPLIT_F)

__global__ __launch_bounds__(256) void sq_kernel(const float* __restrict__ x,
                                                 const float* __restrict__ embed,
                                                 float* __restrict__ x2,
                                                 float* __restrict__ e2) {
  int wid  = threadIdx.x >> 6;
  int lane = threadIdx.x & 63;
  int rid  = blockIdx.x * 4 + wid;
  const float* base = (rid < NROWS) ? (x + (size_t)rid * D)
                                    : (embed + (size_t)(rid - NROWS) * D);
  float4 v = *(const float4*)(base + lane * 4);
  float p = v.x * v.x + v.y * v.y + v.z * v.z + v.w * v.w;
  #pragma unroll
  for (int off = 32; off > 0; off >>= 1) p += __shfl_down(p, off);
  if (lane == 0) {
    if (rid < NROWS) x2[rid] = p;
    else             e2[rid - NROWS] = p;
  }
}

__global__ __launch_bounds__(256) void argmin_f32_kernel(const float* __restrict__ x,
                                                         const float* __restrict__ embed,
                                                         const float* __restrict__ x2,
                                                         const float* __restrict__ e2,
                                                         float* __restrict__ pVal,
                                                         int* __restrict__ pIdx) {
  __shared__ float As[BK_F][BM_F];
  __shared__ float Bs[BK_F][BN_F];
  const int tid = threadIdx.x;
  const int ty = tid >> 4, tx = tid & 15;
  const int rowBase = blockIdx.x * BM_F;
  const int split = blockIdx.y;
  const int r0 = ty * 8, c0 = tx * 8;
  float bestV[8]; int bestI[8];
  #pragma unroll
  for (int i = 0; i < 8; i++) { bestV[i] = -INFINITY; bestI[i] = 0; }
  float x2r[8];
  #pragma unroll
  for (int i = 0; i < 8; i++) x2r[i] = x2[rowBase + r0 + i];
  for (int chunk = 0; chunk < SPLIT_CF / BN_F; ++chunk) {
    const int cBase = split * SPLIT_CF + chunk * BN_F;
    float acc[8][8];
    #pragma unroll
    for (int i = 0; i < 8; i++)
      #pragma unroll
      for (int j = 0; j < 8; j++) acc[i][j] = 0.0f;
    for (int kb = 0; kb < D / BK_F; ++kb) {
      #pragma unroll
      for (int i = 0; i < 4; i++) {
        int f4 = tid + i * 256;
        int rr = f4 >> 3, k4 = f4 & 7;
        float4 va = *(const float4*)&x[(size_t)(rowBase + rr) * D + kb * BK_F + k4 * 4];
        As[k4 * 4 + 0][rr] = va.x; As[k4 * 4 + 1][rr] = va.y;
        As[k4 * 4 + 2][rr] = va.z; As[k4 * 4 + 3][rr] = va.w;
        float4 vb = *(const float4*)&embed[(size_t)(cBase + rr) * D + kb * BK_F + k4 * 4];
        Bs[k4 * 4 + 0][rr] = vb.x; Bs[k4 * 4 + 1][rr] = vb.y;
        Bs[k4 * 4 + 2][rr] = vb.z; Bs[k4 * 4 + 3][rr] = vb.w;
      }
      __syncthreads();
      #pragma unroll 8
      for (int kk = 0; kk < BK_F; kk++) {
        float a[8], b[8];
        *(float4*)&a[0] = *(const float4*)&As[kk][r0];
        *(float4*)&a[4] = *(const float4*)&As[kk][r0 + 4];
        *(float4*)&b[0] = *(const float4*)&Bs[kk][c0];
        *(float4*)&b[4] = *(const float4*)&Bs[kk][c0 + 4];
        #pragma unroll
        for (int i = 0; i < 8; i++)
          #pragma unroll
          for (int j = 0; j < 8; j++)
            acc[i][j] = fmaf(a[i], b[j], acc[i][j]);
      }
      __syncthreads();
    }
    #pragma unroll
    for (int j = 0; j < 8; j++) {
      int c = cBase + c0 + j;
      float e2c = e2[c];
      #pragma unroll
      for (int i = 0; i < 8; i++) {
        float s  = __fadd_rn(x2r[i], e2c);
        float u  = __fmul_rn(2.0f, acc[i][j]);
        float d2 = fmaxf(__fsub_rn(s, u), 0.0f);
        float dist = -sqrtf(d2);
        if (dist > bestV[i]) { bestV[i] = dist; bestI[i] = c; }
      }
    }
  }
  __syncthreads();
  float* Vl = &As[0][0];
  int*   Il = (int*)&Bs[0][0];
  #pragma unroll
  for (int i = 0; i < 8; i++) {
    Vl[(ty * 16 + tx) * 8 + i] = bestV[i];
    Il[(ty * 16 + tx) * 8 + i] = bestI[i];
  }
  __syncthreads();
  if (tid < BM_F) {
    int rr = tid, tyr = rr >> 3, ii = rr & 7;
    float bv = -INFINITY; int bi = 0;
    #pragma unroll
    for (int t = 0; t < 16; t++) {
      float v = Vl[(tyr * 16 + t) * 8 + ii];
      int  iv = Il[(tyr * 16 + t) * 8 + ii];
      if (v > bv || (v == bv && iv < bi)) { bv = v; bi = iv; }
    }
    pVal[split * NROWS + rowBase + rr] = bv;
    pIdx[split * NROWS + rowBase + rr] = bi;
  }
}

__global__ __launch_bounds__(256) void merge_f32_kernel(const float* __restrict__ pVal,
                                                        const int* __restrict__ pIdx,
                                                        float* __restrict__ indF) {
  int row = blockIdx.x * 256 + threadIdx.x;
  if (row >= NROWS) return;
  float bv = -INFINITY; int bi = 0;
  #pragma unroll
  for (int s = 0; s < NSPLIT_F; s++) {
    float v = pVal[s * NROWS + row];
    int  iv = pIdx[s * NROWS + row];
    if (v > bv || (v == bv && iv < bi)) { bv = v; bi = iv; }
  }
  indF[row] = (float)bi;
}

__global__ __launch_bounds__(256) void gather_f32_kernel(const float* __restrict__ embed,
                                                         const float* __restrict__ indF,
                                                         float* __restrict__ outQ) {
  int wid = threadIdx.x >> 6, lane = threadIdx.x & 63;
  int row = blockIdx.x * 4 + wid;
  int idx = (int)indF[row];
  float4 v = *(const float4*)&embed[(size_t)idx * D + lane * 4];
  *(float4*)&outQ[(size_t)row * D + lane * 4] = v;
}

// ---------------------------------------------------------------------------
extern "C" void kernel_launch(void* const* d_in, const int* in_sizes, int n_in,
                              void* d_out, int out_size, void* d_ws, size_t ws_size,
                              hipStream_t stream) {
  const float* x     = (const float*)d_in[0];
  const float* embed = (const float*)d_in[1];
  float* o = (float*)d_out;

  if (ws_size >= WS_NEED2) {
    char* w = (char*)d_ws;
    unsigned short* A_h = (unsigned short*)(w + OFF_AH);
    float* x2 = (float*)(w + OFF_X2);
    float* nx = (float*)(w + OFF_NX);
    float* e2 = (float*)(w + OFF_E2);
    unsigned* rowMinU = (unsigned*)(w + OFF_RM);
    unsigned long long* pKey = (unsigned long long*)(w + OFF_PK);
    unsigned* misc = (unsigned*)(w + OFF_MISC);
    unsigned* list2 = (unsigned*)(w + OFF_L2);
    uint2* cand = (uint2*)(w + OFF_CAND);
    unsigned capN = (unsigned)((ws_size - OFF_CAND) / 8ull);
    if (capN > 6291456u) capN = 6291456u;

    unsigned short* E_h = (unsigned short*)o;   // 4 MB scratch in quantize region
    float* indF = o + QOFF;

    init_kernel<<<128, 256, 0, stream>>>(misc, rowMinU, pKey);
    prep_kernel<<<(NROWS + CODES) / 4, 256, 0, stream>>>(x, embed, A_h, E_h, x2, nx, e2, misc);
    dim3 gridC(NROWS / BM, NSPL);
    coarse_kernel<<<gridC, 256, 0, stream>>>(A_h, E_h, x2, e2, nx, misc, rowMinU, cand, misc, capN);
    filter_kernel<<<2048, 256, 0, stream>>>(cand, misc, rowMinU, nx, list2, capN);
    refine_kernel<<<4096, 256, 0, stream>>>(x, embed, x2, e2, misc, list2, pKey);
    final_kernel<<<NROWS / 4, 256, 0, stream>>>(embed, pKey, o, indF);
  } else {
    // ---- fp32 fallback ----
    float* x2   = o;
    float* e2   = o + 32768;
    float* pVal = o + 65536;
    int*   pIdx = (int*)(o + 196608);
    float* indF = o + QOFF;
    sq_kernel<<<(NROWS + CODES) / 4, 256, 0, stream>>>(x, embed, x2, e2);
    dim3 gridB(NROWS / BM_F, NSPLIT_F);
    argmin_f32_kernel<<<gridB, 256, 0, stream>>>(x, embed, x2, e2, pVal, pIdx);
    merge_f32_kernel<<<NROWS / 256, 256, 0, stream>>>(pVal, pIdx, indF);
    gather_f32_kernel<<<NROWS / 4, 256, 0, stream>>>(embed, indF, o);
  }
}

// Round 4
// 842.668 us; speedup vs baseline: 21.9237x; 21.9237x over previous
//
#include <hip/hip_runtime.h>
#include <math.h>

#define D       256
#define NROWS   32768      // 8 * 4096
#define CODES   8192
#define QOFF    8388608    // index output offset (floats) in d_out

// ---------------- coarse kernel config ----------------
#define BM      128
#define BN      128
#define NSPL    4
#define SPLC    (CODES / NSPL)    // 2048
#define NCHUNK  (SPLC / BN)       // 16
#define PRESCAN 2
#define LCAP    3072              // LDS candidate buffer entries per block

// rigorous collect margin (2M): 2*2*(2u+u^2)*||x||*||e||max, u=2^-9 (bf16 rn)
// = 0.01566*||x||*||e||max; 0.016 adds fp32-accumulation slack.
#define MARG_COEF 0.016f
#define MARG_ABS  0.10f

// ---------------- ws layout (bytes) ----------------
#define OFF_AH    0ull               // 32768*256*2      = 16777216
#define OFF_X2    16777216ull        // 32768*4
#define OFF_NX    16908288ull        // 32768*4
#define OFF_E2    17039360ull        // 8192*4
#define OFF_RM    17072128ull        // 32768*4 (unsigned float-bits)
#define OFF_PK    17203200ull        // 32768*8
#define OFF_MISC  17465344ull        // [0]=cnt, [1]=cnt2, [2]=neMaxBits
#define OFF_L2    17465600ull        // 1048576*4
#define OFF_CAND  21659904ull        // uint2 entries, runtime cap
#define CAP2      1048576u
#define WS_NEED2  (OFF_CAND + 16777216ull)   // proven available (round 2: 51MB)

typedef __attribute__((ext_vector_type(8))) short bf16x8;
typedef __attribute__((ext_vector_type(4))) float f32x4;

// Involutive LDS swizzle (verified 0-conflict in rounds 2-3)
__device__ __forceinline__ int SW(int b) { return b ^ (((b >> 7) & 3) << 4); }

__device__ __forceinline__ void gload16(const void* g, void* l) {
  __builtin_amdgcn_global_load_lds(
      (const __attribute__((address_space(1))) unsigned int*)g,
      (__attribute__((address_space(3))) unsigned int*)l, 16, 0, 0);
}

__device__ __forceinline__ unsigned short bf16rn(float x) {
  unsigned u = __float_as_uint(x);
  return (unsigned short)((u + 0x7fffu + ((u >> 16) & 1u)) >> 16);
}

// ---------------------------------------------------------------------------
// init: zero counters, rowMin=+inf, pKey=~0
// ---------------------------------------------------------------------------
__global__ __launch_bounds__(256) void init_kernel(unsigned* __restrict__ misc,
                                                   unsigned* __restrict__ rowMinU,
                                                   unsigned long long* __restrict__ pKey) {
  int i = blockIdx.x * 256 + threadIdx.x;   // grid 128*256 = 32768
  if (i == 0) { misc[0] = 0u; misc[1] = 0u; misc[2] = 0u; }
  rowMinU[i] = 0x7F800000u;
  pKey[i] = ~0ull;
}

// ---------------------------------------------------------------------------
// prep: bf16 h-planes of x and embed + squared norms + neMax.
// ---------------------------------------------------------------------------
__global__ __launch_bounds__(256) void prep_kernel(const float* __restrict__ x,
                                                   const float* __restrict__ embed,
                                                   unsigned short* __restrict__ A_h,
                                                   unsigned short* __restrict__ E_h,
                                                   float* __restrict__ x2,
                                                   float* __restrict__ nx,
                                                   float* __restrict__ e2,
                                                   unsigned* __restrict__ misc) {
  int wid  = threadIdx.x >> 6;
  int lane = threadIdx.x & 63;
  int rid  = blockIdx.x * 4 + wid;   // 0..40959
  const float* src;
  unsigned short* dst;
  if (rid < NROWS) { src = x + (size_t)rid * D;               dst = A_h + (size_t)rid * D; }
  else             { src = embed + (size_t)(rid - NROWS) * D; dst = E_h + (size_t)(rid - NROWS) * D; }
  float4 v = *(const float4*)(src + lane * 4);
  ushort4 hv = make_ushort4(bf16rn(v.x), bf16rn(v.y), bf16rn(v.z), bf16rn(v.w));
  *(ushort4*)(dst + lane * 4) = hv;
  float p = v.x * v.x + v.y * v.y + v.z * v.z + v.w * v.w;
  #pragma unroll
  for (int off = 32; off > 0; off >>= 1) p += __shfl_down(p, off);
  if (lane == 0) {
    float n = sqrtf(p);
    if (rid < NROWS) { x2[rid] = p; nx[rid] = n; }
    else { e2[rid - NROWS] = p; atomicMax(&misc[2], __float_as_uint(n)); }
  }
}

// ---------------------------------------------------------------------------
// coarse: 1-plane bf16 MFMA GEMM + running per-row min + margin-collection.
// Collection is LDS-buffered: shared-atomic append, one global atomicAdd per
// block per chunk at flush (coalesced copy). Overflow -> direct global (rare).
// ---------------------------------------------------------------------------
__global__ __launch_bounds__(256) void coarse_kernel(
    const unsigned short* __restrict__ A_h,
    const unsigned short* __restrict__ E_h,
    const float* __restrict__ x2g, const float* __restrict__ e2g,
    const float* __restrict__ nxg, const unsigned* __restrict__ miscR,
    unsigned* __restrict__ rowMinU,
    uint2* __restrict__ cand, unsigned* __restrict__ cnt, unsigned capN) {
  __shared__ __align__(16) char As[8192];
  __shared__ __align__(16) char Bs[8192];
  __shared__ float seedBuf[2][128];
  __shared__ uint2 lbuf[LCAP];
  __shared__ unsigned lcnt, lbaseS, lnS;

  const int tid  = threadIdx.x;
  const int lane = tid & 63;
  const int wave = tid >> 6;
  const int wm = wave >> 1, wn = wave & 1;
  const int l15 = lane & 15, lh = lane >> 4;
  const int rowBase = blockIdx.x * BM;
  const int split   = blockIdx.y;

  int swA[4], swB[4];
  #pragma unroll
  for (int f = 0; f < 4; f++) {
    swA[f] = SW((((wm * 64 + f * 16 + l15)) << 6) | (lh << 4));
    swB[f] = SW((((wn * 64 + f * 16 + l15)) << 6) | (lh << 4));
  }

  int stRow[2], stOff[2], stDst[2];
  #pragma unroll
  for (int i = 0; i < 2; i++) {
    int q = i * 256 + tid;           // 0..511 (16B slots of the 8KB tile)
    int u = SW(q << 4);
    stRow[i] = u >> 6;
    stOff[i] = u & 63;
    stDst[i] = (q & ~63) * 16;
  }

  const float neMaxF = __uint_as_float(miscR[2]);

  float x2r[16], rowC[16];
  int rowIdx[16];
  #pragma unroll
  for (int fm = 0; fm < 4; fm++)
    #pragma unroll
    for (int r = 0; r < 4; r++) {
      int s = fm * 4 + r;
      int row = rowBase + wm * 64 + fm * 16 + lh * 4 + r;
      rowIdx[s] = row;
      x2r[s] = x2g[row];
      rowC[s] = fmaf(MARG_COEF * nxg[row], neMaxF, MARG_ABS);
    }

  float runm[16];
  #pragma unroll
  for (int s = 0; s < 16; s++) runm[s] = INFINITY;

  // ---------------- prescan (seed the running min) ----------------
  for (int cc = 0; cc < PRESCAN; ++cc) {
    const int cBase = split * SPLC + cc * BN;
    f32x4 acc[4][4];
    #pragma unroll
    for (int i = 0; i < 4; i++)
      #pragma unroll
      for (int j = 0; j < 4; j++) acc[i][j] = (f32x4)(0.0f);
    for (int kb = 0; kb < 8; ++kb) {
      __syncthreads();
      #pragma unroll
      for (int i = 0; i < 2; i++) {
        gload16((const char*)A_h + (size_t)(rowBase + stRow[i]) * 512 + kb * 64 + stOff[i], As + stDst[i]);
        gload16((const char*)E_h + (size_t)(cBase   + stRow[i]) * 512 + kb * 64 + stOff[i], Bs + stDst[i]);
      }
      __syncthreads();
      bf16x8 af[4], bf[4];
      #pragma unroll
      for (int f = 0; f < 4; f++) { af[f] = *(const bf16x8*)(As + swA[f]); bf[f] = *(const bf16x8*)(Bs + swB[f]); }
      #pragma unroll
      for (int fm = 0; fm < 4; fm++)
        #pragma unroll
        for (int fn = 0; fn < 4; fn++)
          acc[fm][fn] = __builtin_amdgcn_mfma_f32_16x16x32_bf16(af[fm], bf[fn], acc[fm][fn], 0, 0, 0);
    }
    #pragma unroll
    for (int fn = 0; fn < 4; fn++) {
      float e2c = e2g[cBase + wn * 64 + fn * 16 + l15];
      #pragma unroll
      for (int fm = 0; fm < 4; fm++)
        #pragma unroll
        for (int r = 0; r < 4; r++) {
          int s = fm * 4 + r;
          float d2 = fmaf(acc[fm][fn][r], -2.0f, x2r[s] + e2c);
          runm[s] = fminf(runm[s], d2);
        }
    }
  }
  // reduce seed across l15 lanes and the two wn waves
  #pragma unroll
  for (int s = 0; s < 16; s++)
    #pragma unroll
    for (int off = 1; off < 16; off <<= 1)
      runm[s] = fminf(runm[s], __shfl_xor(runm[s], off));
  __syncthreads();
  if (l15 == 0) {
    #pragma unroll
    for (int s = 0; s < 16; s++) seedBuf[wn][rowIdx[s] - rowBase] = runm[s];
  }
  if (tid == 0) lcnt = 0;
  __syncthreads();
  float thr[16];
  #pragma unroll
  for (int s = 0; s < 16; s++) {
    int rl = rowIdx[s] - rowBase;
    runm[s] = fminf(seedBuf[0][rl], seedBuf[1][rl]);
  }

  // ---------------- main scan with collection ----------------
  for (int cc = 0; cc < NCHUNK; ++cc) {
    const int cBase = split * SPLC + cc * BN;
    f32x4 acc[4][4];
    #pragma unroll
    for (int i = 0; i < 4; i++)
      #pragma unroll
      for (int j = 0; j < 4; j++) acc[i][j] = (f32x4)(0.0f);
    for (int kb = 0; kb < 8; ++kb) {
      __syncthreads();
      #pragma unroll
      for (int i = 0; i < 2; i++) {
        gload16((const char*)A_h + (size_t)(rowBase + stRow[i]) * 512 + kb * 64 + stOff[i], As + stDst[i]);
        gload16((const char*)E_h + (size_t)(cBase   + stRow[i]) * 512 + kb * 64 + stOff[i], Bs + stDst[i]);
      }
      __syncthreads();
      bf16x8 af[4], bf[4];
      #pragma unroll
      for (int f = 0; f < 4; f++) { af[f] = *(const bf16x8*)(As + swA[f]); bf[f] = *(const bf16x8*)(Bs + swB[f]); }
      #pragma unroll
      for (int fm = 0; fm < 4; fm++)
        #pragma unroll
        for (int fn = 0; fn < 4; fn++)
          acc[fm][fn] = __builtin_amdgcn_mfma_f32_16x16x32_bf16(af[fm], bf[fn], acc[fm][fn], 0, 0, 0);
    }

    // ---- pass 1: include this chunk in the running min, cross-lane reduce ----
    #pragma unroll
    for (int fn = 0; fn < 4; fn++) {
      float e2c = e2g[cBase + wn * 64 + fn * 16 + l15];
      #pragma unroll
      for (int fm = 0; fm < 4; fm++)
        #pragma unroll
        for (int r = 0; r < 4; r++) {
          int s = fm * 4 + r;
          float d2 = fmaf(acc[fm][fn][r], -2.0f, x2r[s] + e2c);
          runm[s] = fminf(runm[s], d2);
        }
    }
    #pragma unroll
    for (int s = 0; s < 16; s++) {
      #pragma unroll
      for (int off = 1; off < 16; off <<= 1)
        runm[s] = fminf(runm[s], __shfl_xor(runm[s], off));
      thr[s] = runm[s] + rowC[s];
    }

    // ---- pass 2: collect with the fresh threshold (LDS append) ----
    #pragma unroll
    for (int fn = 0; fn < 4; fn++) {
      int col = cBase + wn * 64 + fn * 16 + l15;
      float e2c = e2g[col];
      #pragma unroll
      for (int fm = 0; fm < 4; fm++)
        #pragma unroll
        for (int r = 0; r < 4; r++) {
          int s = fm * 4 + r;
          float d2 = fmaf(acc[fm][fn][r], -2.0f, x2r[s] + e2c);
          if (d2 <= thr[s]) {
            unsigned p = atomicAdd(&lcnt, 1u);
            uint2 en = make_uint2((unsigned)((rowIdx[s] << 13) | col), __float_as_uint(d2));
            if (p < LCAP) lbuf[p] = en;
            else {                                  // rare overflow: direct
              unsigned gp = atomicAdd(cnt, 1u);
              if (gp < capN) cand[gp] = en;
            }
          }
        }
    }

    // ---- flush LDS buffer: one global atomic per block per chunk ----
    __syncthreads();
    if (tid == 0) {
      unsigned n = lcnt; if (n > LCAP) n = LCAP;
      lnS = n;
      lbaseS = n ? atomicAdd(cnt, n) : 0u;
    }
    __syncthreads();
    for (unsigned i = tid; i < lnS; i += 256) {
      unsigned gp = lbaseS + i;
      if (gp < capN) cand[gp] = lbuf[i];
    }
    if (tid == 0) lcnt = 0;
    // reset/copy hazards covered by the next chunk's first __syncthreads()
  }

  // ---------------- final per-row coarse min ----------------
  if (l15 == 0) {
    #pragma unroll
    for (int s = 0; s < 16; s++)
      atomicMin(&rowMinU[rowIdx[s]], __float_as_uint(fmaxf(runm[s], 0.0f)));
  }
}

// ---------------------------------------------------------------------------
// filter: re-test candidates against the FINAL rowMin, compact survivors.
// ---------------------------------------------------------------------------
__global__ __launch_bounds__(256) void filter_kernel(const uint2* __restrict__ cand,
                                                     unsigned* __restrict__ misc,
                                                     const unsigned* __restrict__ rowMinU,
                                                     const float* __restrict__ nxg,
                                                     unsigned* __restrict__ list2,
                                                     unsigned capN) {
  unsigned total = misc[0]; if (total > capN) total = capN;
  float neMaxF = __uint_as_float(misc[2]);
  unsigned stride = gridDim.x * 256;
  for (unsigned i = blockIdx.x * 256 + threadIdx.x; i < total; i += stride) {
    uint2 en = cand[i];
    unsigned row = en.x >> 13;
    float d2c = __uint_as_float(en.y);
    float rm  = __uint_as_float(rowMinU[row]);
    float rc  = fmaf(MARG_COEF * nxg[row], neMaxF, MARG_ABS);
    if (d2c <= rm + rc) {
      unsigned p = atomicAdd(&misc[1], 1u);
      if (p < CAP2) list2[p] = en.x;
    }
  }
}

// ---------------------------------------------------------------------------
// refine: wave-per-survivor fp64 dot, exact ref combine, u64 atomicMin key.
// ---------------------------------------------------------------------------
__global__ __launch_bounds__(256) void refine_kernel(const float* __restrict__ x,
                                                     const float* __restrict__ embed,
                                                     const float* __restrict__ x2g,
                                                     const float* __restrict__ e2g,
                                                     const unsigned* __restrict__ misc,
                                                     const unsigned* __restrict__ list2,
                                                     unsigned long long* __restrict__ pKey) {
  unsigned total = misc[1]; if (total > CAP2) total = CAP2;
  int lane = threadIdx.x & 63;
  unsigned wv = (blockIdx.x * 256 + threadIdx.x) >> 6;
  unsigned nw = (gridDim.x * 256) >> 6;
  for (unsigned i = wv; i < total; i += nw) {
    unsigned pk = list2[i];
    int row = (int)(pk >> 13), col = (int)(pk & 8191u);
    float4 xv = *(const float4*)&x[(size_t)row * D + lane * 4];
    float4 ev = *(const float4*)&embed[(size_t)col * D + lane * 4];
    double s = (double)xv.x * (double)ev.x;
    s = fma((double)xv.y, (double)ev.y, s);
    s = fma((double)xv.z, (double)ev.z, s);
    s = fma((double)xv.w, (double)ev.w, s);
    #pragma unroll
    for (int off = 32; off > 0; off >>= 1) s += __shfl_down(s, off);
    if (lane == 0) {
      float xef = (float)s;
      float ss  = __fadd_rn(x2g[row], e2g[col]);
      float d2  = __fsub_rn(ss, __fmul_rn(2.0f, xef));
      d2 = fmaxf(d2, 0.0f);
      float sq = sqrtf(d2);
      unsigned long long key =
          ((unsigned long long)__float_as_uint(sq) << 32) | (unsigned)col;
      atomicMin(pKey + row, key);
    }
  }
}

// ---------------------------------------------------------------------------
// finalize: gather codes + write index as float.
// ---------------------------------------------------------------------------
__global__ __launch_bounds__(256) void final_kernel(const float* __restrict__ embed,
                                                    const unsigned long long* __restrict__ pKey,
                                                    float* __restrict__ outQ,
                                                    float* __restrict__ indF) {
  int wid  = threadIdx.x >> 6;
  int lane = threadIdx.x & 63;
  int row  = blockIdx.x * 4 + wid;
  unsigned long long k = pKey[row];
  int idx = (int)(k & 8191ull);
  float4 v = *(const float4*)&embed[(size_t)idx * D + lane * 4];
  *(float4*)&outQ[(size_t)row * D + lane * 4] = v;
  if (lane == 0) indF[row] = (float)idx;
}

// ===========================================================================
// Fallback fp32 path (round-1, proven) — used if ws_size < WS_NEED2.
// ===========================================================================
#define BM_F 128
#define BN_F 128
#define BK_F 32
#define NSPLIT_F 4
#define SPLIT_CF (CODES / NSPLIT_F)

__global__ __launch_bounds__(256) void sq_kernel(const float* __restrict__ x,
                                                 const float* __restrict__ embed,
                                                 float* __restrict__ x2,
                                                 float* __restrict__ e2) {
  int wid  = threadIdx.x >> 6;
  int lane = threadIdx.x & 63;
  int rid  = blockIdx.x * 4 + wid;
  const float* base = (rid < NROWS) ? (x + (size_t)rid * D)
                                    : (embed + (size_t)(rid - NROWS) * D);
  float4 v = *(const float4*)(base + lane * 4);
  float p = v.x * v.x + v.y * v.y + v.z * v.z + v.w * v.w;
  #pragma unroll
  for (int off = 32; off > 0; off >>= 1) p += __shfl_down(p, off);
  if (lane == 0) {
    if (rid < NROWS) x2[rid] = p;
    else             e2[rid - NROWS] = p;
  }
}

__global__ __launch_bounds__(256) void argmin_f32_kernel(const float* __restrict__ x,
                                                         const float* __restrict__ embed,
                                                         const float* __restrict__ x2,
                                                         const float* __restrict__ e2,
                                                         float* __restrict__ pVal,
                                                         int* __restrict__ pIdx) {
  __shared__ float As[BK_F][BM_F];
  __shared__ float Bs[BK_F][BN_F];
  const int tid = threadIdx.x;
  const int ty = tid >> 4, tx = tid & 15;
  const int rowBase = blockIdx.x * BM_F;
  const int split = blockIdx.y;
  const int r0 = ty * 8, c0 = tx * 8;
  float bestV[8]; int bestI[8];
  #pragma unroll
  for (int i = 0; i < 8; i++) { bestV[i] = -INFINITY; bestI[i] = 0; }
  float x2r[8];
  #pragma unroll
  for (int i = 0; i < 8; i++) x2r[i] = x2[rowBase + r0 + i];
  for (int chunk = 0; chunk < SPLIT_CF / BN_F; ++chunk) {
    const int cBase = split * SPLIT_CF + chunk * BN_F;
    float acc[8][8];
    #pragma unroll
    for (int i = 0; i < 8; i++)
      #pragma unroll
      for (int j = 0; j < 8; j++) acc[i][j] = 0.0f;
    for (int kb = 0; kb < D / BK_F; ++kb) {
      #pragma unroll
      for (int i = 0; i < 4; i++) {
        int f4 = tid + i * 256;
        int rr = f4 >> 3, k4 = f4 & 7;
        float4 va = *(const float4*)&x[(size_t)(rowBase + rr) * D + kb * BK_F + k4 * 4];
        As[k4 * 4 + 0][rr] = va.x; As[k4 * 4 + 1][rr] = va.y;
        As[k4 * 4 + 2][rr] = va.z; As[k4 * 4 + 3][rr] = va.w;
        float4 vb = *(const float4*)&embed[(size_t)(cBase + rr) * D + kb * BK_F + k4 * 4];
        Bs[k4 * 4 + 0][rr] = vb.x; Bs[k4 * 4 + 1][rr] = vb.y;
        Bs[k4 * 4 + 2][rr] = vb.z; Bs[k4 * 4 + 3][rr] = vb.w;
      }
      __syncthreads();
      #pragma unroll 8
      for (int kk = 0; kk < BK_F; kk++) {
        float a[8], b[8];
        *(float4*)&a[0] = *(const float4*)&As[kk][r0];
        *(float4*)&a[4] = *(const float4*)&As[kk][r0 + 4];
        *(float4*)&b[0] = *(const float4*)&Bs[kk][c0];
        *(float4*)&b[4] = *(const float4*)&Bs[kk][c0 + 4];
        #pragma unroll
        for (int i = 0; i < 8; i++)
          #pragma unroll
          for (int j = 0; j < 8; j++)
            acc[i][j] = fmaf(a[i], b[j], acc[i][j]);
      }
      __syncthreads();
    }
    #pragma unroll
    for (int j = 0; j < 8; j++) {
      int c = cBase + c0 + j;
      float e2c = e2[c];
      #pragma unroll
      for (int i = 0; i < 8; i++) {
        float s  = __fadd_rn(x2r[i], e2c);
        float u  = __fmul_rn(2.0f, acc[i][j]);
        float d2 = fmaxf(__fsub_rn(s, u), 0.0f);
        float dist = -sqrtf(d2);
        if (dist > bestV[i]) { bestV[i] = dist; bestI[i] = c; }
      }
    }
  }
  __syncthreads();
  float* Vl = &As[0][0];
  int*   Il = (int*)&Bs[0][0];
  #pragma unroll
  for (int i = 0; i < 8; i++) {
    Vl[(ty * 16 + tx) * 8 + i] = bestV[i];
    Il[(ty * 16 + tx) * 8 + i] = bestI[i];
  }
  __syncthreads();
  if (tid < BM_F) {
    int rr = tid, tyr = rr >> 3, ii = rr & 7;
    float bv = -INFINITY; int bi = 0;
    #pragma unroll
    for (int t = 0; t < 16; t++) {
      float v = Vl[(tyr * 16 + t) * 8 + ii];
      int  iv = Il[(tyr * 16 + t) * 8 + ii];
      if (v > bv || (v == bv && iv < bi)) { bv = v; bi = iv; }
    }
    pVal[split * NROWS + rowBase + rr] = bv;
    pIdx[split * NROWS + rowBase + rr] = bi;
  }
}

__global__ __launch_bounds__(256) void merge_f32_kernel(const float* __restrict__ pVal,
                                                        const int* __restrict__ pIdx,
                                                        float* __restrict__ indF) {
  int row = blockIdx.x * 256 + threadIdx.x;
  if (row >= NROWS) return;
  float bv = -INFINITY; int bi = 0;
  #pragma unroll
  for (int s = 0; s < NSPLIT_F; s++) {
    float v = pVal[s * NROWS + row];
    int  iv = pIdx[s * NROWS + row];
    if (v > bv || (v == bv && iv < bi)) { bv = v; bi = iv; }
  }
  indF[row] = (float)bi;
}

__global__ __launch_bounds__(256) void gather_f32_kernel(const float* __restrict__ embed,
                                                         const float* __restrict__ indF,
                                                         float* __restrict__ outQ) {
  int wid = threadIdx.x >> 6, lane = threadIdx.x & 63;
  int row = blockIdx.x * 4 + wid;
  int idx = (int)indF[row];
  float4 v = *(const float4*)&embed[(size_t)idx * D + lane * 4];
  *(float4*)&outQ[(size_t)row * D + lane * 4] = v;
}

// ---------------------------------------------------------------------------
extern "C" void kernel_launch(void* const* d_in, const int* in_sizes, int n_in,
                              void* d_out, int out_size, void* d_ws, size_t ws_size,
                              hipStream_t stream) {
  const float* x     = (const float*)d_in[0];
  const float* embed = (const float*)d_in[1];
  float* o = (float*)d_out;

  if (ws_size >= WS_NEED2) {
    char* w = (char*)d_ws;
    unsigned short* A_h = (unsigned short*)(w + OFF_AH);
    float* x2 = (float*)(w + OFF_X2);
    float* nx = (float*)(w + OFF_NX);
    float* e2 = (float*)(w + OFF_E2);
    unsigned* rowMinU = (unsigned*)(w + OFF_RM);
    unsigned long long* pKey = (unsigned long long*)(w + OFF_PK);
    unsigned* misc = (unsigned*)(w + OFF_MISC);
    unsigned* list2 = (unsigned*)(w + OFF_L2);
    uint2* cand = (uint2*)(w + OFF_CAND);
    unsigned capN = (unsigned)((ws_size - OFF_CAND) / 8ull);
    if (capN > 6291456u) capN = 6291456u;

    unsigned short* E_h = (unsigned short*)o;   // 4 MB scratch in quantize region
    float* indF = o + QOFF;

    init_kernel<<<128, 256, 0, stream>>>(misc, rowMinU, pKey);
    prep_kernel<<<(NROWS + CODES) / 4, 256, 0, stream>>>(x, embed, A_h, E_h, x2, nx, e2, misc);
    dim3 gridC(NROWS / BM, NSPL);
    coarse_kernel<<<gridC, 256, 0, stream>>>(A_h, E_h, x2, e2, nx, misc, rowMinU, cand, misc, capN);
    filter_kernel<<<2048, 256, 0, stream>>>(cand, misc, rowMinU, nx, list2, capN);
    refine_kernel<<<4096, 256, 0, stream>>>(x, embed, x2, e2, misc, list2, pKey);
    final_kernel<<<NROWS / 4, 256, 0, stream>>>(embed, pKey, o, indF);
  } else {
    // ---- fp32 fallback ----
    float* x2   = o;
    float* e2   = o + 32768;
    float* pVal = o + 65536;
    int*   pIdx = (int*)(o + 196608);
    float* indF = o + QOFF;
    sq_kernel<<<(NROWS + CODES) / 4, 256, 0, stream>>>(x, embed, x2, e2);
    dim3 gridB(NROWS / BM_F, NSPLIT_F);
    argmin_f32_kernel<<<gridB, 256, 0, stream>>>(x, embed, x2, e2, pVal, pIdx);
    merge_f32_kernel<<<NROWS / 256, 256, 0, stream>>>(pVal, pIdx, indF);
    gather_f32_kernel<<<NROWS / 4, 256, 0, stream>>>(embed, indF, o);
  }
}

// Round 5
// 488.776 us; speedup vs baseline: 37.7973x; 1.7240x over previous
//
#include <hip/hip_runtime.h>
#include <math.h>

#define D       256
#define NROWS   32768      // 8 * 4096
#define CODES   8192
#define QOFF    8388608    // index output offset (floats) in d_out

// ---------------- coarse GEMM config ----------------
#define BM      128
#define BN      128
#define BK      64
#define NSPL    4
#define SPLC    (CODES / NSPL)    // 2048
#define NCHUNK  (SPLC / BN)       // 16
#define NBLK    1024              // total coarse blocks = 256 * NSPL
#define LQ      4096              // LDS candidate buffer entries (pass 2)

// rigorous collect margin (2M): 2*2*(2u+u^2)*||x||*||e||max, u=2^-9 (bf16 rn)
#define MARG_COEF 0.016f
#define MARG_ABS  0.10f

// ---------------- ws layout (bytes) ----------------
#define OFF_AH    0ull               // 32768*512 = 16777216
#define OFF_X2    16777216ull
#define OFF_NX    16908288ull
#define OFF_E2    17039360ull
#define OFF_RM    17072128ull        // 32768*4 (monotone-encoded float bits)
#define OFF_PK    17203200ull        // 32768*8
#define OFF_MISC  17465344ull        // [1]=ovCnt, [2]=neMaxBits
#define OFF_BCNT  17465600ull        // 1024*4
#define OFF_CAND  17469696ull        // 4B entries (row<<13|col)
#define WS_NEED3  38441216ull        // OFF_CAND + 20MB (proven: ws >= 51MB)

typedef __attribute__((ext_vector_type(8)))  short bf16x8;
typedef __attribute__((ext_vector_type(16))) float f32x16;

// Involutive swizzle for 128B LDS rows: bits 6:4 ^= row bits 2:0 (addr 9:7).
__device__ __forceinline__ int SWK(int b) { return b ^ (((b >> 7) & 7) << 4); }

__device__ __forceinline__ void gload16(const void* g, void* l) {
  __builtin_amdgcn_global_load_lds(
      (const __attribute__((address_space(1))) unsigned int*)g,
      (__attribute__((address_space(3))) unsigned int*)l, 16, 0, 0);
}

__device__ __forceinline__ unsigned short bf16rn(float x) {
  unsigned u = __float_as_uint(x);
  return (unsigned short)((u + 0x7fffu + ((u >> 16) & 1u)) >> 16);
}

// monotone float <-> uint (order-preserving incl. negatives)
__device__ __forceinline__ unsigned encf(float f) {
  unsigned b = __float_as_uint(f);
  return (b >> 31) ? ~b : (b | 0x80000000u);
}
__device__ __forceinline__ float decf(unsigned u) {
  return __uint_as_float((u >> 31) ? (u ^ 0x80000000u) : ~u);
}

// ---------------------------------------------------------------------------
__global__ __launch_bounds__(256) void init_kernel(unsigned* __restrict__ misc,
                                                   unsigned* __restrict__ rowMinU,
                                                   unsigned long long* __restrict__ pKey) {
  int i = blockIdx.x * 256 + threadIdx.x;   // 32768
  if (i < 16) misc[i] = 0u;
  rowMinU[i] = 0xFFFFFFFFu;
  pKey[i] = ~0ull;
}

// ---------------------------------------------------------------------------
// prep: bf16 h-planes + squared norms + neMax (same tree as rounds 1-4).
// ---------------------------------------------------------------------------
__global__ __launch_bounds__(256) void prep_kernel(const float* __restrict__ x,
                                                   const float* __restrict__ embed,
                                                   unsigned short* __restrict__ A_h,
                                                   unsigned short* __restrict__ E_h,
                                                   float* __restrict__ x2,
                                                   float* __restrict__ nx,
                                                   float* __restrict__ e2,
                                                   unsigned* __restrict__ misc) {
  int wid  = threadIdx.x >> 6;
  int lane = threadIdx.x & 63;
  int rid  = blockIdx.x * 4 + wid;   // 0..40959
  const float* src;
  unsigned short* dst;
  if (rid < NROWS) { src = x + (size_t)rid * D;               dst = A_h + (size_t)rid * D; }
  else             { src = embed + (size_t)(rid - NROWS) * D; dst = E_h + (size_t)(rid - NROWS) * D; }
  float4 v = *(const float4*)(src + lane * 4);
  ushort4 hv = make_ushort4(bf16rn(v.x), bf16rn(v.y), bf16rn(v.z), bf16rn(v.w));
  *(ushort4*)(dst + lane * 4) = hv;
  float p = v.x * v.x + v.y * v.y + v.z * v.z + v.w * v.w;
  #pragma unroll
  for (int off = 32; off > 0; off >>= 1) p += __shfl_down(p, off);
  if (lane == 0) {
    float n = sqrtf(p);
    if (rid < NROWS) { x2[rid] = p; nx[rid] = n; }
    else { e2[rid - NROWS] = p; atomicMax(&misc[2], __float_as_uint(n)); }
  }
}

// ---------------------------------------------------------------------------
// gemm_pass<0>: per-row min of q = e2 - 2*xe  (x2 cancels for argmin).
// gemm_pass<1>: collect (row,col) with q <= rowMin + margin into per-block
//               segment (LDS-buffered, single flush). Identical GEMM code =>
//               bit-identical q between passes => min-achiever always kept.
// Tile 128x128, 4 waves (2x2), 2x2 frags of mfma_f32_32x32x16_bf16, BK=64.
// ---------------------------------------------------------------------------
template<int MODE>
__global__ __launch_bounds__(256, 2) void gemm_pass(
    const unsigned short* __restrict__ A_h,
    const unsigned short* __restrict__ E_h,
    const float* __restrict__ e2g,
    const float* __restrict__ nxg,
    const unsigned* __restrict__ miscR,
    unsigned* __restrict__ rowMinU,
    unsigned* __restrict__ cand,        // segmented: seg*Q
    unsigned* __restrict__ blkCnt,
    unsigned* __restrict__ ovCnt,       // &misc[1]
    unsigned Q, unsigned OVCAP) {
  __shared__ __align__(16) char As[16384];   // 128 rows x 128B (BK=64 bf16)
  __shared__ __align__(16) char Bs[16384];
  __shared__ unsigned lbuf[MODE ? LQ : 1];
  __shared__ unsigned lcnt;

  const int tid  = threadIdx.x;
  const int lane = tid & 63;
  const int wave = tid >> 6;
  const int wm = wave >> 1, wn = wave & 1;
  const int l31 = lane & 31;
  const int lh4 = (lane >> 5) * 4;
  const int rowBase = blockIdx.x * BM;
  const int split   = blockIdx.y;
  const int seg     = blockIdx.y * 256 + blockIdx.x;

  // fragment LDS byte offsets (row stride 128B, swizzled)
  int swA[2][4], swB[2][4];
  #pragma unroll
  for (int f = 0; f < 2; f++)
    #pragma unroll
    for (int ks = 0; ks < 4; ks++) {
      int byt = ks * 32 + (lane >> 5) * 16;
      swA[f][ks] = SWK(((wm * 64 + f * 32 + l31) << 7) + byt);
      swB[f][ks] = SWK(((wn * 64 + f * 32 + l31) << 7) + byt);
    }

  // staging slots: 4 gload16 each for A and B per kb step (16KB tiles)
  int stRow[4], stCo[4], stDst[4];
  #pragma unroll
  for (int i = 0; i < 4; i++) {
    int q = i * 256 + tid;          // 0..1023 16B-slot
    int u = SWK(q << 4);            // logical byte (involution)
    stRow[i] = u >> 7;
    stCo[i]  = u & 127;
    stDst[i] = (q & ~63) << 4;      // wave-uniform base
  }

  float state[2][16];   // MODE0: running min q; MODE1: thresholds
  if (MODE == 0) {
    #pragma unroll
    for (int f = 0; f < 2; f++)
      #pragma unroll
      for (int rg = 0; rg < 16; rg++) state[f][rg] = INFINITY;
  } else {
    float neMaxF = __uint_as_float(miscR[2]);
    #pragma unroll
    for (int f = 0; f < 2; f++)
      #pragma unroll
      for (int rg = 0; rg < 16; rg++) {
        int row = rowBase + wm * 64 + f * 32 + ((rg & 3) + 8 * (rg >> 2)) + lh4;
        state[f][rg] = decf(rowMinU[row]) + fmaf(MARG_COEF * nxg[row], neMaxF, MARG_ABS);
      }
    if (tid == 0) lcnt = 0;
  }

  for (int cc = 0; cc < NCHUNK; ++cc) {
    const int cBase = split * SPLC + cc * BN;

    f32x16 acc[2][2];
    #pragma unroll
    for (int i = 0; i < 2; i++)
      #pragma unroll
      for (int j = 0; j < 2; j++) acc[i][j] = (f32x16)(0.0f);

    for (int kb = 0; kb < 4; ++kb) {
      __syncthreads();
      #pragma unroll
      for (int i = 0; i < 4; i++) {
        gload16((const char*)A_h + (((size_t)(rowBase + stRow[i])) << 9) + (kb << 7) + stCo[i],
                As + stDst[i]);
        gload16((const char*)E_h + (((size_t)(cBase + stRow[i])) << 9) + (kb << 7) + stCo[i],
                Bs + stDst[i]);
      }
      __syncthreads();
      #pragma unroll
      for (int ks = 0; ks < 4; ++ks) {
        bf16x8 a0 = *(const bf16x8*)(As + swA[0][ks]);
        bf16x8 a1 = *(const bf16x8*)(As + swA[1][ks]);
        bf16x8 b0 = *(const bf16x8*)(Bs + swB[0][ks]);
        bf16x8 b1 = *(const bf16x8*)(Bs + swB[1][ks]);
        acc[0][0] = __builtin_amdgcn_mfma_f32_32x32x16_bf16(a0, b0, acc[0][0], 0, 0, 0);
        acc[0][1] = __builtin_amdgcn_mfma_f32_32x32x16_bf16(a0, b1, acc[0][1], 0, 0, 0);
        acc[1][0] = __builtin_amdgcn_mfma_f32_32x32x16_bf16(a1, b0, acc[1][0], 0, 0, 0);
        acc[1][1] = __builtin_amdgcn_mfma_f32_32x32x16_bf16(a1, b1, acc[1][1], 0, 0, 0);
      }
    }

    // epilogue: q = e2 - 2*xe  (C/D map: row=(rg&3)+8*(rg>>2)+lh4, col=l31)
    #pragma unroll
    for (int fn = 0; fn < 2; fn++) {
      int col = cBase + wn * 64 + fn * 32 + l31;
      float e2c = e2g[col];
      #pragma unroll
      for (int fm = 0; fm < 2; fm++)
        #pragma unroll
        for (int rg = 0; rg < 16; rg++) {
          float q = fmaf(acc[fm][fn][rg], -2.0f, e2c);
          if (MODE == 0) {
            state[fm][rg] = fminf(state[fm][rg], q);
          } else if (q <= state[fm][rg]) {
            int row = rowBase + wm * 64 + fm * 32 + ((rg & 3) + 8 * (rg >> 2)) + lh4;
            unsigned en = (unsigned)((row << 13) | col);
            unsigned p = atomicAdd(&lcnt, 1u);
            if (p < LQ) lbuf[p] = en;
            else { unsigned gp = atomicAdd(ovCnt, 1u);
                   if (gp < OVCAP) cand[(size_t)NBLK * Q + gp] = en; }
          }
        }
    }
  }

  if (MODE == 0) {
    // single final reduce across the 32 col-lanes, then encoded atomicMin
    #pragma unroll
    for (int fm = 0; fm < 2; fm++)
      #pragma unroll
      for (int rg = 0; rg < 16; rg++) {
        float v = state[fm][rg];
        #pragma unroll
        for (int off = 1; off < 32; off <<= 1) v = fminf(v, __shfl_xor(v, off));
        if (l31 == 0) {
          int row = rowBase + wm * 64 + fm * 32 + ((rg & 3) + 8 * (rg >> 2)) + lh4;
          atomicMin(&rowMinU[row], encf(v));
        }
      }
  } else {
    __syncthreads();
    unsigned n = lcnt; if (n > LQ) n = LQ;
    for (unsigned i = tid; i < n; i += 256) cand[(size_t)seg * Q + i] = lbuf[i];
    if (tid == 0) blkCnt[seg] = n;
  }
}

// ---------------------------------------------------------------------------
// refine: 16-lane groups, fp64 dot, exact ref combine, u64 atomicMin key.
// Block b handles segment b, then grid-strides the overflow list.
// ---------------------------------------------------------------------------
__global__ __launch_bounds__(256) void refine_kernel(const float* __restrict__ x,
                                                     const float* __restrict__ embed,
                                                     const float* __restrict__ x2g,
                                                     const float* __restrict__ e2g,
                                                     const unsigned* __restrict__ blkCnt,
                                                     const unsigned* __restrict__ cand,
                                                     const unsigned* __restrict__ miscR,
                                                     unsigned long long* __restrict__ pKey,
                                                     unsigned Q, unsigned OVCAP) {
  const int tid = threadIdx.x;
  const int l16 = tid & 15;
  const int gid = tid >> 4;              // 0..15 groups per block

  auto doItem = [&](unsigned pk) {
    int row = (int)(pk >> 13), col = (int)(pk & 8191u);
    double s = 0.0;
    #pragma unroll
    for (int p = 0; p < 4; p++) {
      float4 xv = *(const float4*)&x[(size_t)row * D + p * 64 + l16 * 4];
      float4 ev = *(const float4*)&embed[(size_t)col * D + p * 64 + l16 * 4];
      s = fma((double)xv.x, (double)ev.x, s);
      s = fma((double)xv.y, (double)ev.y, s);
      s = fma((double)xv.z, (double)ev.z, s);
      s = fma((double)xv.w, (double)ev.w, s);
    }
    #pragma unroll
    for (int off = 1; off < 16; off <<= 1) s += __shfl_xor(s, off);
    if (l16 == 0) {
      float xef = (float)s;
      float ss  = __fadd_rn(x2g[row], e2g[col]);
      float d2  = __fsub_rn(ss, __fmul_rn(2.0f, xef));
      d2 = fmaxf(d2, 0.0f);
      float sq = sqrtf(d2);
      unsigned long long key =
          ((unsigned long long)__float_as_uint(sq) << 32) | (unsigned)col;
      atomicMin(pKey + row, key);
    }
  };

  unsigned seg = blockIdx.x;             // 1024 blocks
  unsigned n = blkCnt[seg]; if (n > LQ) n = LQ;
  const unsigned* segp = cand + (size_t)seg * Q;
  for (unsigned i = gid; i < n; i += 16) doItem(segp[i]);

  unsigned ov = miscR[1]; if (ov > OVCAP) ov = OVCAP;
  const unsigned* ovp = cand + (size_t)NBLK * Q;
  for (unsigned i = blockIdx.x * 16 + gid; i < ov; i += NBLK * 16) doItem(ovp[i]);
}

// ---------------------------------------------------------------------------
// finalize: gather codes + write index as float.
// ---------------------------------------------------------------------------
__global__ __launch_bounds__(256) void final_kernel(const float* __restrict__ embed,
                                                    const unsigned long long* __restrict__ pKey,
                                                    float* __restrict__ outQ,
                                                    float* __restrict__ indF) {
  int wid  = threadIdx.x >> 6;
  int lane = threadIdx.x & 63;
  int row  = blockIdx.x * 4 + wid;
  unsigned long long k = pKey[row];
  int idx = (int)(k & 8191ull);
  float4 v = *(const float4*)&embed[(size_t)idx * D + lane * 4];
  *(float4*)&outQ[(size_t)row * D + lane * 4] = v;
  if (lane == 0) indF[row] = (float)idx;
}

// ===========================================================================
// Fallback fp32 path (round-1, proven) — used if ws_size < WS_NEED3.
// ===========================================================================
#define BM_F 128
#define BN_F 128
#define BK_F 32
#define NSPLIT_F 4
#define SPLIT_CF (CODES / NSPLIT_F)

__global__ __launch_bounds__(256) void sq_kernel(const float* __restrict__ x,
                                                 const float* __restrict__ embed,
                                                 float* __restrict__ x2,
                                                 float* __restrict__ e2) {
  int wid  = threadIdx.x >> 6;
  int lane = threadIdx.x & 63;
  int rid  = blockIdx.x * 4 + wid;
  const float* base = (rid < NROWS) ? (x + (size_t)rid * D)
                                    : (embed + (size_t)(rid - NROWS) * D);
  float4 v = *(const float4*)(base + lane * 4);
  float p = v.x * v.x + v.y * v.y + v.z * v.z + v.w * v.w;
  #pragma unroll
  for (int off = 32; off > 0; off >>= 1) p += __shfl_down(p, off);
  if (lane == 0) {
    if (rid < NROWS) x2[rid] = p;
    else             e2[rid - NROWS] = p;
  }
}

__global__ __launch_bounds__(256) void argmin_f32_kernel(const float* __restrict__ x,
                                                         const float* __restrict__ embed,
                                                         const float* __restrict__ x2,
                                                         const float* __restrict__ e2,
                                                         float* __restrict__ pVal,
                                                         int* __restrict__ pIdx) {
  __shared__ float As[BK_F][BM_F];
  __shared__ float Bs[BK_F][BN_F];
  const int tid = threadIdx.x;
  const int ty = tid >> 4, tx = tid & 15;
  const int rowBase = blockIdx.x * BM_F;
  const int split = blockIdx.y;
  const int r0 = ty * 8, c0 = tx * 8;
  float bestV[8]; int bestI[8];
  #pragma unroll
  for (int i = 0; i < 8; i++) { bestV[i] = -INFINITY; bestI[i] = 0; }
  float x2r[8];
  #pragma unroll
  for (int i = 0; i < 8; i++) x2r[i] = x2[rowBase + r0 + i];
  for (int chunk = 0; chunk < SPLIT_CF / BN_F; ++chunk) {
    const int cBase = split * SPLIT_CF + chunk * BN_F;
    float acc[8][8];
    #pragma unroll
    for (int i = 0; i < 8; i++)
      #pragma unroll
      for (int j = 0; j < 8; j++) acc[i][j] = 0.0f;
    for (int kb = 0; kb < D / BK_F; ++kb) {
      #pragma unroll
      for (int i = 0; i < 4; i++) {
        int f4 = tid + i * 256;
        int rr = f4 >> 3, k4 = f4 & 7;
        float4 va = *(const float4*)&x[(size_t)(rowBase + rr) * D + kb * BK_F + k4 * 4];
        As[k4 * 4 + 0][rr] = va.x; As[k4 * 4 + 1][rr] = va.y;
        As[k4 * 4 + 2][rr] = va.z; As[k4 * 4 + 3][rr] = va.w;
        float4 vb = *(const float4*)&embed[(size_t)(cBase + rr) * D + kb * BK_F + k4 * 4];
        Bs[k4 * 4 + 0][rr] = vb.x; Bs[k4 * 4 + 1][rr] = vb.y;
        Bs[k4 * 4 + 2][rr] = vb.z; Bs[k4 * 4 + 3][rr] = vb.w;
      }
      __syncthreads();
      #pragma unroll 8
      for (int kk = 0; kk < BK_F; kk++) {
        float a[8], b[8];
        *(float4*)&a[0] = *(const float4*)&As[kk][r0];
        *(float4*)&a[4] = *(const float4*)&As[kk][r0 + 4];
        *(float4*)&b[0] = *(const float4*)&Bs[kk][c0];
        *(float4*)&b[4] = *(const float4*)&Bs[kk][c0 + 4];
        #pragma unroll
        for (int i = 0; i < 8; i++)
          #pragma unroll
          for (int j = 0; j < 8; j++)
            acc[i][j] = fmaf(a[i], b[j], acc[i][j]);
      }
      __syncthreads();
    }
    #pragma unroll
    for (int j = 0; j < 8; j++) {
      int c = cBase + c0 + j;
      float e2c = e2[c];
      #pragma unroll
      for (int i = 0; i < 8; i++) {
        float s  = __fadd_rn(x2r[i], e2c);
        float u  = __fmul_rn(2.0f, acc[i][j]);
        float d2 = fmaxf(__fsub_rn(s, u), 0.0f);
        float dist = -sqrtf(d2);
        if (dist > bestV[i]) { bestV[i] = dist; bestI[i] = c; }
      }
    }
  }
  __syncthreads();
  float* Vl = &As[0][0];
  int*   Il = (int*)&Bs[0][0];
  #pragma unroll
  for (int i = 0; i < 8; i++) {
    Vl[(ty * 16 + tx) * 8 + i] = bestV[i];
    Il[(ty * 16 + tx) * 8 + i] = bestI[i];
  }
  __syncthreads();
  if (tid < BM_F) {
    int rr = tid, tyr = rr >> 3, ii = rr & 7;
    float bv = -INFINITY; int bi = 0;
    #pragma unroll
    for (int t = 0; t < 16; t++) {
      float v = Vl[(tyr * 16 + t) * 8 + ii];
      int  iv = Il[(tyr * 16 + t) * 8 + ii];
      if (v > bv || (v == bv && iv < bi)) { bv = v; bi = iv; }
    }
    pVal[split * NROWS + rowBase + rr] = bv;
    pIdx[split * NROWS + rowBase + rr] = bi;
  }
}

__global__ __launch_bounds__(256) void merge_f32_kernel(const float* __restrict__ pVal,
                                                        const int* __restrict__ pIdx,
                                                        float* __restrict__ indF) {
  int row = blockIdx.x * 256 + threadIdx.x;
  if (row >= NROWS) return;
  float bv = -INFINITY; int bi = 0;
  #pragma unroll
  for (int s = 0; s < NSPLIT_F; s++) {
    float v = pVal[s * NROWS + row];
    int  iv = pIdx[s * NROWS + row];
    if (v > bv || (v == bv && iv < bi)) { bv = v; bi = iv; }
  }
  indF[row] = (float)bi;
}

__global__ __launch_bounds__(256) void gather_f32_kernel(const float* __restrict__ embed,
                                                         const float* __restrict__ indF,
                                                         float* __restrict__ outQ) {
  int wid = threadIdx.x >> 6, lane = threadIdx.x & 63;
  int row = blockIdx.x * 4 + wid;
  int idx = (int)indF[row];
  float4 v = *(const float4*)&embed[(size_t)idx * D + lane * 4];
  *(float4*)&outQ[(size_t)row * D + lane * 4] = v;
}

// ---------------------------------------------------------------------------
extern "C" void kernel_launch(void* const* d_in, const int* in_sizes, int n_in,
                              void* d_out, int out_size, void* d_ws, size_t ws_size,
                              hipStream_t stream) {
  const float* x     = (const float*)d_in[0];
  const float* embed = (const float*)d_in[1];
  float* o = (float*)d_out;

  if (ws_size >= WS_NEED3) {
    char* w = (char*)d_ws;
    unsigned short* A_h = (unsigned short*)(w + OFF_AH);
    float* x2 = (float*)(w + OFF_X2);
    float* nx = (float*)(w + OFF_NX);
    float* e2 = (float*)(w + OFF_E2);
    unsigned* rowMinU = (unsigned*)(w + OFF_RM);
    unsigned long long* pKey = (unsigned long long*)(w + OFF_PK);
    unsigned* misc = (unsigned*)(w + OFF_MISC);
    unsigned* blkCnt = (unsigned*)(w + OFF_BCNT);
    unsigned* cand = (unsigned*)(w + OFF_CAND);
    unsigned capN  = (unsigned)((ws_size - OFF_CAND) / 4ull);
    unsigned Q     = (capN - 262144u) >> 10;       // per-block segment size
    unsigned OVCAP = capN - (Q << 10);             // overflow region

    unsigned short* E_h = (unsigned short*)o;      // 4MB scratch in quantize region
    float* indF = o + QOFF;

    init_kernel<<<128, 256, 0, stream>>>(misc, rowMinU, pKey);
    prep_kernel<<<(NROWS + CODES) / 4, 256, 0, stream>>>(x, embed, A_h, E_h, x2, nx, e2, misc);
    dim3 gridC(NROWS / BM, NSPL);
    gemm_pass<0><<<gridC, 256, 0, stream>>>(A_h, E_h, e2, nx, misc, rowMinU,
                                            cand, blkCnt, &misc[1], Q, OVCAP);
    gemm_pass<1><<<gridC, 256, 0, stream>>>(A_h, E_h, e2, nx, misc, rowMinU,
                                            cand, blkCnt, &misc[1], Q, OVCAP);
    refine_kernel<<<NBLK, 256, 0, stream>>>(x, embed, x2, e2, blkCnt, cand, misc,
                                            pKey, Q, OVCAP);
    final_kernel<<<NROWS / 4, 256, 0, stream>>>(embed, pKey, o, indF);
  } else {
    // ---- fp32 fallback ----
    float* x2   = o;
    float* e2   = o + 32768;
    float* pVal = o + 65536;
    int*   pIdx = (int*)(o + 196608);
    float* indF = o + QOFF;
    sq_kernel<<<(NROWS + CODES) / 4, 256, 0, stream>>>(x, embed, x2, e2);
    dim3 gridB(NROWS / BM_F, NSPLIT_F);
    argmin_f32_kernel<<<gridB, 256, 0, stream>>>(x, embed, x2, e2, pVal, pIdx);
    merge_f32_kernel<<<NROWS / 256, 256, 0, stream>>>(pVal, pIdx, indF);
    gather_f32_kernel<<<NROWS / 4, 256, 0, stream>>>(embed, indF, o);
  }
}